// Round 5
// baseline (101.995 us; speedup 1.0000x reference)
//
#include <hip/hip_runtime.h>
#include <hip/hip_bf16.h>

// KPConv collapses to: out[c,:] = sum_m s[c,m] * (x[src(c,m),:] @ W[m])
// with s[c,m] = sum of w over neighbors whose argmin kernel point == m.
//
// kw    (16 blocks):  W fp32 [16][64][128] -> Wb bf16 [16][128][64] in ws
//                     (LDS transpose; only ws user, 256 KiB).
// kmain (512 blocks x 256 thr, 16 centers/block):
//   prologue: exact-rounding argmin + influence weights -> s_loc[m][r] in LDS
//             (2 barriers, atomic-free);
//   GEMM:     barrier-free m-loop, MFMA fragments loaded DIRECTLY from global
//             in fragment layout -- A gathered from fp32 x and converted
//             inline to bf16 (identical rounding to a separate cvt pass),
//             B from Wb; s applied post-MFMA in fp32; direct stores, each
//             block owns its 16 output rows (no atomics, no out zeroing).

#define KPE 0.6666667f  // float(1.0/1.5), matches numpy f32 promotion

typedef short short8 __attribute__((ext_vector_type(8)));
typedef float floatx4 __attribute__((ext_vector_type(4)));

__device__ inline unsigned short f2bf(float f) {
    __hip_bfloat16 h = __float2bfloat16(f);
    return __builtin_bit_cast(unsigned short, h);
}

__device__ inline short8 pack8(float4 u, float4 v) {
    short8 r;
    r[0] = (short)f2bf(u.x); r[1] = (short)f2bf(u.y);
    r[2] = (short)f2bf(u.z); r[3] = (short)f2bf(u.w);
    r[4] = (short)f2bf(v.x); r[5] = (short)f2bf(v.y);
    r[6] = (short)f2bf(v.z); r[7] = (short)f2bf(v.w);
    return r;
}

__global__ __launch_bounds__(256) void kw(const float* __restrict__ Wf,
                                          unsigned short* __restrict__ Wb) {
    const int t = threadIdx.x;
    const int m = blockIdx.x;
    __shared__ float tile[64 * 129];                // [i][n], pad 128->129
#pragma unroll
    for (int j = 0; j < 32; ++j) {
        int idx = j * 256 + t;                      // i = idx>>7, n = idx&127
        tile[(idx >> 7) * 129 + (idx & 127)] = Wf[m * 8192 + idx];
    }
    __syncthreads();
#pragma unroll
    for (int j = 0; j < 32; ++j) {
        int idx = j * 256 + t;                      // n = idx>>6, i = idx&63
        Wb[m * 8192 + idx] = f2bf(tile[(idx & 63) * 129 + (idx >> 6)]);
    }
}

__global__ __launch_bounds__(256, 2) void kmain(
    const float* __restrict__ x, const float* __restrict__ pos,
    const int* __restrict__ esrc, const int* __restrict__ etgt,
    const float* __restrict__ kpts, const unsigned short* __restrict__ Wb,
    float* __restrict__ out)
{
    __shared__ float kps[48];
    __shared__ float wv[16 * 17];                  // [r][n] pad 16->17
    __shared__ int   nnv[16 * 17];
    __shared__ __align__(16) int   srcv[16 * 16];  // [r][m]
    __shared__ __align__(16) float s_loc[16 * 16]; // [m][r]

    const int t = threadIdx.x;                     // 256 threads = 4 waves
    if (t < 48) kps[t] = kpts[t];

    // ---- per-edge: argmin kernel point + influence weight (bit-exact) ----
    const int e   = blockIdx.x * 256 + t;          // 16 centers * 16 edges
    const int src = esrc[e];
    const int tgt = etgt[e];
    float rx = __fsub_rn(pos[tgt * 3 + 0], pos[src * 3 + 0]);
    float ry = __fsub_rn(pos[tgt * 3 + 1], pos[src * 3 + 1]);
    float rz = __fsub_rn(pos[tgt * 3 + 2], pos[src * 3 + 2]);
    __syncthreads();                               // kps visible
    float best = 1e30f; int nn = 0;
#pragma unroll
    for (int k = 0; k < 16; ++k) {
        float dx = __fsub_rn(rx, kps[k * 3 + 0]);
        float dy = __fsub_rn(ry, kps[k * 3 + 1]);
        float dz = __fsub_rn(rz, kps[k * 3 + 2]);
        float sq = __fadd_rn(__fadd_rn(__fmul_rn(dx, dx), __fmul_rn(dy, dy)),
                             __fmul_rn(dz, dz));
        if (sq < best) { best = sq; nn = k; }      // strict < == np.argmin
    }
    float w = fmaxf(__fsub_rn(1.0f, __fdiv_rn(__fsqrt_rn(best), KPE)), 0.0f);
    {
        const int r = t >> 4, n = t & 15;
        wv[r * 17 + n] = w; nnv[r * 17 + n] = nn;
        srcv[r * 16 + n] = src;
    }
    __syncthreads();
    {
        const int mm = t >> 4, cl = t & 15;
        float sacc = 0.f;
#pragma unroll
        for (int n2 = 0; n2 < 16; ++n2)
            sacc += (nnv[cl * 17 + n2] == mm) ? wv[cl * 17 + n2] : 0.f;
        s_loc[mm * 16 + cl] = sacc;
    }
    __syncthreads();                               // last barrier

    // ---- barrier-free MFMA GEMM: 16 rows x 128 cols, K = 16 m x 64 ----
    const float4* x4f = reinterpret_cast<const float4*>(x);   // 16 f4 / row
    const uint4*  wb4 = reinterpret_cast<const uint4*>(Wb);   // 1024 u4 / m
    const int wv_ = t >> 6, lane = t & 63;
    const int l16 = lane & 15, quad = lane >> 4;
    const int bc0 = (wv_ * 32 + l16) * 8 + quad;   // B frag base, col half 0
    const int bc1 = bc0 + 128;                     // col half 1 (+16 rows)

    int sidx[16];                                  // all 16 src rows up front
    {
        const int4* sp = reinterpret_cast<const int4*>(&srcv[l16 * 16]);
        int4 q0 = sp[0], q1 = sp[1], q2 = sp[2], q3 = sp[3];
        sidx[0]=q0.x; sidx[1]=q0.y; sidx[2]=q0.z;  sidx[3]=q0.w;
        sidx[4]=q1.x; sidx[5]=q1.y; sidx[6]=q1.z;  sidx[7]=q1.w;
        sidx[8]=q2.x; sidx[9]=q2.y; sidx[10]=q2.z; sidx[11]=q2.w;
        sidx[12]=q3.x; sidx[13]=q3.y; sidx[14]=q3.z; sidx[15]=q3.w;
    }

    float4 A[3][4];                                // 2-ahead ring (fp32 A rows)
    uint4  B[2][4];                                // 1-ahead
    float4 SV[2];
    const int aq = quad * 2;
#pragma unroll
    for (int p = 0; p < 2; ++p) {
        const int sr = sidx[p] * 16;
        A[p][0] = x4f[sr + aq];     A[p][1] = x4f[sr + aq + 1];
        A[p][2] = x4f[sr + 8 + aq]; A[p][3] = x4f[sr + 8 + aq + 1];
    }
    B[0][0] = wb4[bc0]; B[0][1] = wb4[bc0 + 4];
    B[0][2] = wb4[bc1]; B[0][3] = wb4[bc1 + 4];
    SV[0] = *reinterpret_cast<const float4*>(&s_loc[quad * 4]);

    floatx4 acc0 = {0.f, 0.f, 0.f, 0.f};
    floatx4 acc1 = {0.f, 0.f, 0.f, 0.f};
    const floatx4 zed = {0.f, 0.f, 0.f, 0.f};

#pragma unroll
    for (int i = 0; i < 16; ++i) {
        const int cur = i % 3, bcur = i & 1;
        if (i + 2 < 16) {                          // A 2-ahead
            const int sr = sidx[i + 2] * 16, slot = (i + 2) % 3;
            A[slot][0] = x4f[sr + aq];     A[slot][1] = x4f[sr + aq + 1];
            A[slot][2] = x4f[sr + 8 + aq]; A[slot][3] = x4f[sr + 8 + aq + 1];
        }
        if (i + 1 < 16) {                          // B/SV 1-ahead
            const int mb = (i + 1) * 1024, bn = bcur ^ 1;
            B[bn][0] = wb4[mb + bc0]; B[bn][1] = wb4[mb + bc0 + 4];
            B[bn][2] = wb4[mb + bc1]; B[bn][3] = wb4[mb + bc1 + 4];
            SV[bn] = *reinterpret_cast<const float4*>(
                &s_loc[(i + 1) * 16 + quad * 4]);
        }
        const short8 a0 = pack8(A[cur][0], A[cur][1]);
        const short8 a1 = pack8(A[cur][2], A[cur][3]);
        floatx4 t0 = __builtin_amdgcn_mfma_f32_16x16x32_bf16(
            a0, __builtin_bit_cast(short8, B[bcur][0]), zed, 0, 0, 0);
        t0 = __builtin_amdgcn_mfma_f32_16x16x32_bf16(
            a1, __builtin_bit_cast(short8, B[bcur][1]), t0, 0, 0, 0);
        floatx4 t1 = __builtin_amdgcn_mfma_f32_16x16x32_bf16(
            a0, __builtin_bit_cast(short8, B[bcur][2]), zed, 0, 0, 0);
        t1 = __builtin_amdgcn_mfma_f32_16x16x32_bf16(
            a1, __builtin_bit_cast(short8, B[bcur][3]), t1, 0, 0, 0);
        const float4 sv = SV[bcur];
#pragma unroll
        for (int v = 0; v < 4; ++v) {
            const float s4 = (v == 0) ? sv.x : (v == 1) ? sv.y
                           : (v == 2) ? sv.z : sv.w;
            acc0[v] += s4 * t0[v];
            acc1[v] += s4 * t1[v];
        }
    }

    // ---- epilogue: C/D layout col=lane&15, row=quad*4+reg ----
    const int col  = wv_ * 32 + l16;
    const int row0 = blockIdx.x * 16 + quad * 4;
#pragma unroll
    for (int v = 0; v < 4; ++v) {
        out[(row0 + v) * 128 + col]      = acc0[v];
        out[(row0 + v) * 128 + col + 16] = acc1[v];
    }
}

extern "C" void kernel_launch(void* const* d_in, const int* in_sizes, int n_in,
                              void* d_out, int out_size, void* d_ws, size_t ws_size,
                              hipStream_t stream) {
    const float* x    = (const float*)d_in[0];
    const float* pos  = (const float*)d_in[1];
    const int*   esrc = (const int*)d_in[2];
    const int*   etgt = (const int*)d_in[3];
    const float* kpts = (const float*)d_in[4];
    const float* Wf   = (const float*)d_in[5];
    float* out = (float*)d_out;
    unsigned short* Wb = (unsigned short*)d_ws;     // 256 KiB

    hipLaunchKernelGGL(kw,    dim3(16),  dim3(256), 0, stream, Wf, Wb);
    hipLaunchKernelGGL(kmain, dim3(512), dim3(256), 0, stream,
                       x, pos, esrc, etgt, kpts, Wb, out);
}

// Round 6
// 94.301 us; speedup vs baseline: 1.0816x; 1.0816x over previous
//
#include <hip/hip_runtime.h>
#include <hip/hip_bf16.h>

// KPConv collapses to: out[c,:] = sum_m s[c,m] * (x[src(c,m),:] @ W[m])
// with s[c,m] = sum of w over neighbors whose argmin kernel point == m.
//
// R1 frame (best measured: 83.2 us) + two surgical upgrades:
//  - double-buffered LDS: 1 barrier/m-iter instead of 2; A/B/SV prefetched
//    2-ahead into registers.
//  - s applied post-MFMA in fp32 (acc += s_row * (x@W[m])): one less bf16
//    rounding (absmax 0.0156), staging path carries pure bf16(x).
// kw: W fp32 [16][64][128] -> Wb bf16 [16][128][64] via LDS transpose.
// kmain: 256 blocks x 512 thr, 32 centers/block; LDS-staged A (8KB/m shared
// by 8 waves) + B (16KB/m) feeding mfma_f32_16x16x32_bf16.

#define KPE 0.6666667f  // float(1.0/1.5), matches numpy f32 promotion

typedef short short8 __attribute__((ext_vector_type(8)));
typedef float floatx4 __attribute__((ext_vector_type(4)));

__device__ inline unsigned short f2bf(float f) {
    __hip_bfloat16 h = __float2bfloat16(f);
    return __builtin_bit_cast(unsigned short, h);
}

__global__ __launch_bounds__(256) void kw(const float* __restrict__ Wf,
                                          unsigned short* __restrict__ Wb) {
    const int t = threadIdx.x;
    const int m = blockIdx.x;
    __shared__ float tile[64 * 129];                // [i][n], pad 128->129
#pragma unroll
    for (int j = 0; j < 32; ++j) {
        int idx = j * 256 + t;                      // i = idx>>7, n = idx&127
        tile[(idx >> 7) * 129 + (idx & 127)] = Wf[m * 8192 + idx];
    }
    __syncthreads();
#pragma unroll
    for (int j = 0; j < 32; ++j) {
        int idx = j * 256 + t;                      // n = idx>>6, i = idx&63
        Wb[m * 8192 + idx] = f2bf(tile[(idx & 63) * 129 + (idx >> 6)]);
    }
}

__global__ __launch_bounds__(512) void kmain(
    const float* __restrict__ x, const float* __restrict__ pos,
    const int* __restrict__ esrc, const int* __restrict__ etgt,
    const float* __restrict__ kpts, const unsigned short* __restrict__ Wb,
    float* __restrict__ out)
{
    __shared__ float kps[48];
    __shared__ float wv[512];
    __shared__ int   nnv[512];
    __shared__ int   srcv[512];                    // [c_local*16 + m]
    __shared__ __align__(16) float s_loc[512];     // [m*32 + c_local]
    __shared__ __align__(16) unsigned short As[2][32 * 72];   // pad 64->72
    __shared__ __align__(16) unsigned short Bs[2][128 * 72];

    const int t  = threadIdx.x;                    // 512 threads = 8 waves
    const int c0 = blockIdx.x * 32;

    if (t < 48) kps[t] = kpts[t];

    // ---- per-edge: argmin kernel point + influence weight (bit-exact) ----
    const int e   = blockIdx.x * 512 + t;          // 32 centers * 16 edges
    const int src = esrc[e];
    const int tgt = etgt[e];
    float rx = __fsub_rn(pos[tgt * 3 + 0], pos[src * 3 + 0]);
    float ry = __fsub_rn(pos[tgt * 3 + 1], pos[src * 3 + 1]);
    float rz = __fsub_rn(pos[tgt * 3 + 2], pos[src * 3 + 2]);
    __syncthreads();                               // kps visible
    float best = 1e30f; int nn = 0;
#pragma unroll
    for (int k = 0; k < 16; ++k) {
        float dx = __fsub_rn(rx, kps[k * 3 + 0]);
        float dy = __fsub_rn(ry, kps[k * 3 + 1]);
        float dz = __fsub_rn(rz, kps[k * 3 + 2]);
        float sq = __fadd_rn(__fadd_rn(__fmul_rn(dx, dx), __fmul_rn(dy, dy)),
                             __fmul_rn(dz, dz));
        if (sq < best) { best = sq; nn = k; }      // strict < == np.argmin
    }
    float w = fmaxf(__fsub_rn(1.0f, __fdiv_rn(__fsqrt_rn(best), KPE)), 0.0f);
    wv[t] = w; nnv[t] = nn; srcv[t] = src;
    __syncthreads();                               // wv/nnv/srcv visible

    // ---- s[c,m] = sum of w where nn == m; layout [m][c] for float4 SV ----
    {
        const int mm = t >> 5, cl = t & 31;
        float sacc = 0.f;
#pragma unroll
        for (int n2 = 0; n2 < 16; ++n2)
            sacc += (nnv[cl * 16 + n2] == mm) ? wv[cl * 16 + n2] : 0.f;
        s_loc[mm * 32 + cl] = sacc;
    }

    // ---- GEMM setup; issue m=0,1 gathers (srcv stable) ----
    const float4* x4  = reinterpret_cast<const float4*>(x);   // 16 f4 / row
    const uint4*  wb4 = reinterpret_cast<const uint4*>(Wb);   // 1024 u4 / m
    const int ar = t >> 4, aq = t & 15;            // A-fill: row, float4-quarter
    const int ar16 = ar * 16;

    float4 xa[2]; uint4 bv[2][2];
    xa[0]    = x4[srcv[ar16 + 0] * 16 + aq];
    xa[1]    = x4[srcv[ar16 + 1] * 16 + aq];
    bv[0][0] = wb4[t];          bv[0][1] = wb4[512 + t];
    bv[1][0] = wb4[1024 + t];   bv[1][1] = wb4[1536 + t];

    const int wave = t >> 6, lane = t & 63;
    const int rg = wave & 1, cq = wave >> 1;       // row group, col quarter
    const int l16 = lane & 15, quad = lane >> 4;
    const int aoff  = (rg * 16 + l16) * 72;
    const int boff0 = (cq * 32 + l16) * 72;
    const int boff1 = boff0 + 16 * 72;
    const int koff  = quad * 8;
    const int svoff = rg * 16 + quad * 4;

    __syncthreads();                               // s_loc visible
    float4 sv[2];
    sv[0] = *reinterpret_cast<const float4*>(&s_loc[svoff]);
    sv[1] = *reinterpret_cast<const float4*>(&s_loc[32 + svoff]);

    // write buf0 (m=0)
    {
        ushort4 av;
        av.x = f2bf(xa[0].x); av.y = f2bf(xa[0].y);
        av.z = f2bf(xa[0].z); av.w = f2bf(xa[0].w);
        *reinterpret_cast<ushort4*>(&As[0][ar * 72 + aq * 4]) = av;
#pragma unroll
        for (int j = 0; j < 2; ++j) {
            int u = j * 512 + t;                   // n = u>>3, seg = u&7
            *reinterpret_cast<uint4*>(&Bs[0][(u >> 3) * 72 + (u & 7) * 8]) = bv[0][j];
        }
    }
    __syncthreads();                               // buf0 ready

    floatx4 acc0 = {0.f, 0.f, 0.f, 0.f};
    floatx4 acc1 = {0.f, 0.f, 0.f, 0.f};
    const floatx4 zed = {0.f, 0.f, 0.f, 0.f};

#pragma unroll
    for (int m = 0; m < 16; ++m) {
        const int cur = m & 1, nxt = cur ^ 1;
        const float4 svnow = sv[cur];              // copy before slot refill

        if (m < 15) {                              // stage m+1 into buf[nxt]
            ushort4 av;
            av.x = f2bf(xa[nxt].x); av.y = f2bf(xa[nxt].y);
            av.z = f2bf(xa[nxt].z); av.w = f2bf(xa[nxt].w);
            *reinterpret_cast<ushort4*>(&As[nxt][ar * 72 + aq * 4]) = av;
#pragma unroll
            for (int j = 0; j < 2; ++j) {
                int u = j * 512 + t;
                *reinterpret_cast<uint4*>(&Bs[nxt][(u >> 3) * 72 + (u & 7) * 8]) = bv[nxt][j];
            }
        }
        if (m < 14) {                              // prefetch m+2 into slot cur
            xa[cur]    = x4[srcv[ar16 + m + 2] * 16 + aq];
            bv[cur][0] = wb4[(m + 2) * 1024 + t];
            bv[cur][1] = wb4[(m + 2) * 1024 + 512 + t];
            sv[cur]    = *reinterpret_cast<const float4*>(&s_loc[(m + 2) * 32 + svoff]);
        }

        // MFMA on buf[cur], then post-scale by s (fp32)
        floatx4 t0 = zed, t1 = zed;
#pragma unroll
        for (int ks = 0; ks < 2; ++ks) {
            short8 a  = *reinterpret_cast<const short8*>(&As[cur][aoff  + ks * 32 + koff]);
            short8 b0 = *reinterpret_cast<const short8*>(&Bs[cur][boff0 + ks * 32 + koff]);
            t0 = __builtin_amdgcn_mfma_f32_16x16x32_bf16(a, b0, t0, 0, 0, 0);
            short8 b1 = *reinterpret_cast<const short8*>(&Bs[cur][boff1 + ks * 32 + koff]);
            t1 = __builtin_amdgcn_mfma_f32_16x16x32_bf16(a, b1, t1, 0, 0, 0);
        }
#pragma unroll
        for (int v = 0; v < 4; ++v) {
            const float s4 = (v == 0) ? svnow.x : (v == 1) ? svnow.y
                           : (v == 2) ? svnow.z : svnow.w;
            acc0[v] += s4 * t0[v];
            acc1[v] += s4 * t1[v];
        }
        if (m < 15) __syncthreads();               // buf[nxt] ready / buf[cur] free
    }

    // ---- epilogue: C/D layout col=lane&15, row=quad*4+reg ----
    const int col  = cq * 32 + l16;
    const int row0 = c0 + rg * 16 + quad * 4;
#pragma unroll
    for (int v = 0; v < 4; ++v) {
        out[(row0 + v) * 128 + col]      = acc0[v];
        out[(row0 + v) * 128 + col + 16] = acc1[v];
    }
}

extern "C" void kernel_launch(void* const* d_in, const int* in_sizes, int n_in,
                              void* d_out, int out_size, void* d_ws, size_t ws_size,
                              hipStream_t stream) {
    const float* x    = (const float*)d_in[0];
    const float* pos  = (const float*)d_in[1];
    const int*   esrc = (const int*)d_in[2];
    const int*   etgt = (const int*)d_in[3];
    const float* kpts = (const float*)d_in[4];
    const float* Wf   = (const float*)d_in[5];
    float* out = (float*)d_out;
    unsigned short* Wb = (unsigned short*)d_ws;     // 256 KiB

    hipLaunchKernelGGL(kw,    dim3(16),  dim3(256), 0, stream, Wf, Wb);
    hipLaunchKernelGGL(kmain, dim3(256), dim3(512), 0, stream,
                       x, pos, esrc, etgt, kpts, Wb, out);
}